// Round 4
// baseline (4332.524 us; speedup 1.0000x reference)
//
#include <hip/hip_runtime.h>
#include <hip/hip_bf16.h>

#define BATCH 4
#define SEQ   1024
#define DIM   1024
#define NH    16
#define DH    64
#define DFF   4096
#define MTOK  (BATCH*SEQ)   // 4096 token rows

typedef __attribute__((ext_vector_type(8))) short  short8;
typedef __attribute__((ext_vector_type(4))) float  floatx4;
typedef __attribute__((ext_vector_type(4))) float  float4v;

__device__ inline float bf2f(short s) {
    return __uint_as_float(((unsigned int)(unsigned short)s) << 16);
}
__device__ inline short f2bf(float f) {
    __hip_bfloat16 h = __float2bfloat16(f);
    return *reinterpret_cast<short*>(&h);
}

__device__ inline float wave_sum(float v) {
    #pragma unroll
    for (int off = 32; off >= 1; off >>= 1) v += __shfl_xor(v, off);
    return v;
}

// ---------------------------------------------------------------------------
// NT GEMM: C[M,N] = A[M,K] * B[N,K]^T, fp32 accum, bf16 out.
// A is fp32 (AFP32=1) or bf16 ws intermediate (AFP32=0); B always fp32
// weights, converted to bf16 fragments in-register.
// Block = 256 thr (4 waves), tile 64x64; wave w owns rows 16w..16w+15.
// Fragment layouts (m89/m92/m120 HW-verified):
//   A: m=lane&15, k=quad*8+j   B: n=lane&15, k=quad*8+j
//   C/D: col=lane&15, row=quad*4+reg
// epi: 0 = store; 1 = +bias(f32), SELU; 2 = +bias(f32), +resid(bf16).
// ---------------------------------------------------------------------------
template<int AFP32>
__global__ __launch_bounds__(256) void gemm_nt(
    const void* __restrict__ Av, const float* __restrict__ B,
    const float* __restrict__ bias, const short* __restrict__ resid,
    short* __restrict__ C, int M, int N, int K, int epi)
{
    const int lane = threadIdx.x & 63;
    const int wave = threadIdx.x >> 6;
    const int quad = lane >> 4;
    const int l15  = lane & 15;
    const int tm = blockIdx.x * 64;
    const int tn = blockIdx.y * 64;
    const int arow = tm + wave*16 + l15;

    const float* Ar_f = (const float*)Av + (size_t)arow * K + quad*8;
    const short* Ar_b = (const short*)Av + (size_t)arow * K + quad*8;
    const float* Br   = B + (size_t)(tn + l15) * K + quad*8;

    floatx4 acc[4];
    #pragma unroll
    for (int nt = 0; nt < 4; nt++) acc[nt] = {0.f, 0.f, 0.f, 0.f};

    for (int k0 = 0; k0 < K; k0 += 32) {
        short8 a;
        if (AFP32) {
            float4v f0 = *(const float4v*)(Ar_f + k0);
            float4v f1 = *(const float4v*)(Ar_f + k0 + 4);
            a[0]=f2bf(f0[0]); a[1]=f2bf(f0[1]); a[2]=f2bf(f0[2]); a[3]=f2bf(f0[3]);
            a[4]=f2bf(f1[0]); a[5]=f2bf(f1[1]); a[6]=f2bf(f1[2]); a[7]=f2bf(f1[3]);
        } else {
            a = *(const short8*)(Ar_b + k0);
        }
        #pragma unroll
        for (int nt = 0; nt < 4; nt++) {
            const float* bp = Br + (size_t)(nt*16) * K + k0;
            float4v g0 = *(const float4v*)(bp);
            float4v g1 = *(const float4v*)(bp + 4);
            short8 bb;
            bb[0]=f2bf(g0[0]); bb[1]=f2bf(g0[1]); bb[2]=f2bf(g0[2]); bb[3]=f2bf(g0[3]);
            bb[4]=f2bf(g1[0]); bb[5]=f2bf(g1[1]); bb[6]=f2bf(g1[2]); bb[7]=f2bf(g1[3]);
            acc[nt] = __builtin_amdgcn_mfma_f32_16x16x32_bf16(a, bb, acc[nt], 0, 0, 0);
        }
    }

    const float SELU_SCALE = 1.0507009873554805f;
    const float SELU_ALPHA = 1.6732632423543772f;

    #pragma unroll
    for (int nt = 0; nt < 4; nt++) {
        int col = tn + nt*16 + l15;
        #pragma unroll
        for (int r = 0; r < 4; r++) {
            int row = tm + wave*16 + quad*4 + r;
            float v = acc[nt][r];
            if (epi == 1) {
                v += bias[col];
                v = (v > 0.f) ? SELU_SCALE * v
                              : SELU_SCALE * SELU_ALPHA * (expf(v) - 1.f);
            } else if (epi == 2) {
                v += bias[col] + bf2f(resid[(size_t)row * N + col]);
            }
            C[(size_t)row * N + col] = f2bf(v);
        }
    }
}

// ---------------------------------------------------------------------------
// Obviously-correct flash attention: one wave per (b, h, query row).
// Lane = head dim (DH=64 == wavefront). Dot products via wave_sum; scalar
// online softmax replicated across lanes; per-lane O accumulator.
// No MFMA fragment-layout assumptions anywhere.
// ---------------------------------------------------------------------------
__global__ __launch_bounds__(256) void attn_row(
    const short* __restrict__ Q, const short* __restrict__ K,
    const short* __restrict__ V, short* __restrict__ CTX)
{
    const int wid  = blockIdx.x * 4 + (threadIdx.x >> 6);
    const int lane = threadIdx.x & 63;
    const int q  = wid & (SEQ - 1);
    const int bh = wid >> 10;
    const int b  = bh >> 4;
    const int h  = bh & 15;

    const size_t base = (size_t)b * SEQ * DIM + (size_t)h * DH + lane;
    const float qv = bf2f(Q[base + (size_t)q * DIM]);
    const short* Kp = K + base;
    const short* Vp = V + base;

    float m = -3.0e38f, l = 0.f, o = 0.f;
    for (int j = 0; j <= q; j++) {
        float kv = bf2f(Kp[(size_t)j * DIM]);
        float s  = wave_sum(qv * kv) * 0.125f;        // 1/sqrt(DH)
        float mn = fmaxf(m, s);
        float al = expf(m - mn);                      // first iter: 0
        float p  = expf(s - mn);
        l = l * al + p;
        o = o * al + p * bf2f(Vp[(size_t)j * DIM]);
        m = mn;
    }
    CTX[base + (size_t)q * DIM] = f2bf(o / l);
}

// ---------------------------------------------------------------------------
// Row LayerNorm over D=1024. xa is fp32 (xa_fp32=1) or bf16; optional bf16
// second input added. g/b fp32. One block per row; biased variance, eps 1e-5.
// OUTF32: 1 -> write float (final output), 0 -> write bf16 (intermediate).
// ---------------------------------------------------------------------------
template<int OUTF32>
__global__ __launch_bounds__(256) void ln_kernel(
    const void* __restrict__ xav, int xa_fp32, const short* __restrict__ xb,
    const float* __restrict__ g, const float* __restrict__ bvec,
    void* __restrict__ outv)
{
    __shared__ float red[8];
    const size_t base = (size_t)blockIdx.x * DIM;
    const int wave = threadIdx.x >> 6;

    float x[4];
    float sum = 0.f, sq = 0.f;
    #pragma unroll
    for (int i = 0; i < 4; i++) {
        int idx = threadIdx.x + i*256;
        float v = xa_fp32 ? ((const float*)xav)[base + idx]
                          : bf2f(((const short*)xav)[base + idx]);
        if (xb) v += bf2f(xb[base + idx]);
        x[i] = v; sum += v; sq += v*v;
    }
    sum = wave_sum(sum); sq = wave_sum(sq);
    if ((threadIdx.x & 63) == 0) { red[wave] = sum; red[4 + wave] = sq; }
    __syncthreads();
    float s1 = red[0] + red[1] + red[2] + red[3];
    float s2 = red[4] + red[5] + red[6] + red[7];
    float mean = s1 * (1.f / DIM);
    float var  = s2 * (1.f / DIM) - mean * mean;
    float rstd = rsqrtf(var + 1e-5f);
    #pragma unroll
    for (int i = 0; i < 4; i++) {
        int idx = threadIdx.x + i*256;
        float r = (x[i] - mean) * rstd * g[idx] + bvec[idx];
        if (OUTF32) ((float*)outv)[base + idx] = r;
        else        ((short*)outv)[base + idx] = f2bf(r);
    }
}

// ---------------------------------------------------------------------------
// Workspace plan (48 MB):
//   [ 0, 8M): Q      \
//   [ 8,16M): K       | dead after attn/ln1 -> overlaid by Hf (32 MB)
//   [16,24M): V       |
//   [24,32M): CTX    /
//   [32,40M): X1 (residual for FFN2)
//   [40,48M): Y2 (bf16 FFN2 output; LN2 reads it, writes FP32 to d_out)
// d_out is float* (reference output dtype is float32).
// ---------------------------------------------------------------------------
extern "C" void kernel_launch(void* const* d_in, const int* in_sizes, int n_in,
                              void* d_out, int out_size, void* d_ws, size_t ws_size,
                              hipStream_t stream)
{
    const float* X   = (const float*)d_in[0];
    const float* wq  = (const float*)d_in[1];
    const float* wk  = (const float*)d_in[2];
    const float* wv  = (const float*)d_in[3];
    const float* g1  = (const float*)d_in[4];
    const float* b1  = (const float*)d_in[5];
    const float* w1  = (const float*)d_in[6];
    const float* bb1 = (const float*)d_in[7];
    const float* w2  = (const float*)d_in[8];
    const float* bb2 = (const float*)d_in[9];
    const float* g2  = (const float*)d_in[10];
    const float* b2  = (const float*)d_in[11];

    short* ws = (short*)d_ws;
    const size_t E4 = 4194304;            // 4M elements = 8 MB bf16
    short* Q   = ws;
    short* Kb  = ws + 1*E4;
    short* V   = ws + 2*E4;
    short* CTX = ws + 3*E4;
    short* X1  = ws + 4*E4;
    short* Hf  = ws;                      // 16M elements, overlays Q..CTX
    short* Y2  = ws + 5*E4;

    dim3 blk(256);
    gemm_nt<1><<<dim3(MTOK/64, DIM/64), blk, 0, stream>>>(X, wq, nullptr, nullptr, Q,  MTOK, DIM, DIM, 0);
    gemm_nt<1><<<dim3(MTOK/64, DIM/64), blk, 0, stream>>>(X, wk, nullptr, nullptr, Kb, MTOK, DIM, DIM, 0);
    gemm_nt<1><<<dim3(MTOK/64, DIM/64), blk, 0, stream>>>(X, wv, nullptr, nullptr, V,  MTOK, DIM, DIM, 0);
    attn_row<<<dim3(BATCH*NH*SEQ/4), blk, 0, stream>>>(Q, Kb, V, CTX);
    ln_kernel<0><<<dim3(MTOK), blk, 0, stream>>>(X, 1, CTX, g1, b1, X1);
    gemm_nt<0><<<dim3(MTOK/64, DFF/64), blk, 0, stream>>>(X1, w1, bb1, nullptr, Hf, MTOK, DFF, DIM, 1);
    gemm_nt<0><<<dim3(MTOK/64, DIM/64), blk, 0, stream>>>(Hf, w2, bb2, X1, Y2, MTOK, DIM, DFF, 2);
    ln_kernel<1><<<dim3(MTOK), blk, 0, stream>>>(Y2, 0, nullptr, g2, b2, d_out);
}

// Round 5
// 1037.741 us; speedup vs baseline: 4.1750x; 4.1750x over previous
//
#include <hip/hip_runtime.h>
#include <hip/hip_bf16.h>

#define BATCH 4
#define SEQ   1024
#define DIM   1024
#define NH    16
#define DH    64
#define DFF   4096
#define MTOK  (BATCH*SEQ)   // 4096 token rows

typedef __attribute__((ext_vector_type(8))) short  short8;
typedef __attribute__((ext_vector_type(4))) float  floatx4;
typedef __attribute__((ext_vector_type(4))) float  float4v;

__device__ inline float bf2f(short s) {
    return __uint_as_float(((unsigned int)(unsigned short)s) << 16);
}
__device__ inline short f2bf(float f) {
    __hip_bfloat16 h = __float2bfloat16(f);
    return *reinterpret_cast<short*>(&h);
}

__device__ inline float wave_sum(float v) {
    #pragma unroll
    for (int off = 32; off >= 1; off >>= 1) v += __shfl_xor(v, off);
    return v;
}

// ---------------------------------------------------------------------------
// fp32 -> bf16 bulk conversion (n multiple of 8). ~memory-bound.
// ---------------------------------------------------------------------------
__global__ __launch_bounds__(256) void convert_bf16(
    const float* __restrict__ src, short* __restrict__ dst, int n)
{
    int i = (blockIdx.x * 256 + threadIdx.x) * 8;
    if (i >= n) return;
    float4v f0 = *(const float4v*)(src + i);
    float4v f1 = *(const float4v*)(src + i + 4);
    short8 o;
    o[0]=f2bf(f0[0]); o[1]=f2bf(f0[1]); o[2]=f2bf(f0[2]); o[3]=f2bf(f0[3]);
    o[4]=f2bf(f1[0]); o[5]=f2bf(f1[1]); o[6]=f2bf(f1[2]); o[7]=f2bf(f1[3]);
    *(short8*)(dst + i) = o;
}

// ---------------------------------------------------------------------------
// NT GEMM: C[M,N] = A[M,K] * B[N,K]^T, bf16 in, fp32 accum, bf16 out.
// Block = 256 thr (4 waves), tile 64x64; wave w owns rows 16w..16w+15.
// Fragment layouts (m89/m92 HW-verified; field-validated R2==R3):
//   A: m=lane&15, k=quad*8+j   B: n=lane&15, k=quad*8+j
//   C/D: col=lane&15, row=quad*4+reg
// epi: 0 = store; 1 = +bias(f32), SELU; 2 = +bias(f32), +resid(bf16).
// ---------------------------------------------------------------------------
__global__ __launch_bounds__(256) void gemm_nt(
    const short* __restrict__ A, const short* __restrict__ B,
    const float* __restrict__ bias, const short* __restrict__ resid,
    short* __restrict__ C, int M, int N, int K, int epi)
{
    const int lane = threadIdx.x & 63;
    const int wave = threadIdx.x >> 6;
    const int quad = lane >> 4;
    const int l15  = lane & 15;
    const int tm = blockIdx.x * 64;
    const int tn = blockIdx.y * 64;

    const short* Arow  = A + (size_t)(tm + wave*16 + l15) * K + quad*8;
    const short* Bbase = B + (size_t)(tn + l15) * K + quad*8;

    floatx4 acc[4];
    #pragma unroll
    for (int nt = 0; nt < 4; nt++) acc[nt] = {0.f, 0.f, 0.f, 0.f};

    for (int k0 = 0; k0 < K; k0 += 32) {
        short8 a = *(const short8*)(Arow + k0);
        #pragma unroll
        for (int nt = 0; nt < 4; nt++) {
            short8 b = *(const short8*)(Bbase + (size_t)(nt*16) * K + k0);
            acc[nt] = __builtin_amdgcn_mfma_f32_16x16x32_bf16(a, b, acc[nt], 0, 0, 0);
        }
    }

    const float SELU_SCALE = 1.0507009873554805f;
    const float SELU_ALPHA = 1.6732632423543772f;

    #pragma unroll
    for (int nt = 0; nt < 4; nt++) {
        int col = tn + nt*16 + l15;
        #pragma unroll
        for (int r = 0; r < 4; r++) {
            int row = tm + wave*16 + quad*4 + r;
            float v = acc[nt][r];
            if (epi == 1) {
                v += bias[col];
                v = (v > 0.f) ? SELU_SCALE * v
                              : SELU_SCALE * SELU_ALPHA * (expf(v) - 1.f);
            } else if (epi == 2) {
                v += bias[col] + bf2f(resid[(size_t)row * N + col]);
            }
            C[(size_t)row * N + col] = f2bf(v);
        }
    }
}

// ---------------------------------------------------------------------------
// MFMA flash attention (validated by R2==R3 cross-check). Grid =
// (SEQ/64, BATCH*NH); block = 256. Wave owns 16 query rows of a 64-row
// Q tile. QK^T via MFMA with direct global K loads; online softmax in
// registers (state per quad-row); P through LDS (C-layout write, A-layout
// read); V transposed in LDS so PV B-fragments are contiguous 16B reads.
// ---------------------------------------------------------------------------
__global__ __launch_bounds__(256) void attn_kernel(
    const short* __restrict__ Q, const short* __restrict__ K,
    const short* __restrict__ V, short* __restrict__ CTX)
{
    __shared__ __align__(16) short Vt[64][72];      // [d][key], +pad
    __shared__ __align__(16) short Pl[4][16][72];   // [wave][qrow][key], +pad

    const int lane = threadIdx.x & 63;
    const int wave = threadIdx.x >> 6;
    const int quad = lane >> 4;
    const int l15  = lane & 15;
    const int q0 = blockIdx.x * 64;
    const int bh = blockIdx.y;
    const int b  = bh >> 4;
    const int h  = bh & 15;

    const size_t headoff = (size_t)b * SEQ * DIM + (size_t)h * DH;
    const short* Qb = Q + headoff;
    const short* Kb = K + headoff;
    const short* Vb = V + headoff;

    const short* qrow = Qb + (size_t)(q0 + wave*16 + l15) * DIM + quad*8;
    short8 aq0 = *(const short8*)(qrow);
    short8 aq1 = *(const short8*)(qrow + 32);

    float m_s[4], l_s[4];
    floatx4 o[4];
    #pragma unroll
    for (int r = 0; r < 4; r++) { m_s[r] = -3.0e38f; l_s[r] = 0.f; }
    #pragma unroll
    for (int nt = 0; nt < 4; nt++) o[nt] = {0.f, 0.f, 0.f, 0.f};

    for (int j0 = 0; j0 <= q0; j0 += 64) {
        __syncthreads();   // previous iter's Vt reads done
        // stage V^T into LDS: 512 x 16B chunks over 256 threads
        #pragma unroll
        for (int it = 0; it < 2; it++) {
            int idx = threadIdx.x + it * 256;
            int key = idx >> 3;
            int dc  = idx & 7;
            short8 v = *(const short8*)(Vb + (size_t)(j0 + key) * DIM + dc * 8);
            #pragma unroll
            for (int e = 0; e < 8; e++) Vt[dc*8 + e][key] = v[e];
        }
        __syncthreads();

        // S = Q K^T for this wave's 16 rows x 64 keys
        floatx4 s[4];
        #pragma unroll
        for (int nt = 0; nt < 4; nt++) s[nt] = {0.f, 0.f, 0.f, 0.f};
        #pragma unroll
        for (int nt = 0; nt < 4; nt++) {
            const short* kr = Kb + (size_t)(j0 + nt*16 + l15) * DIM + quad*8;
            short8 bk0 = *(const short8*)(kr);
            short8 bk1 = *(const short8*)(kr + 32);
            s[nt] = __builtin_amdgcn_mfma_f32_16x16x32_bf16(aq0, bk0, s[nt], 0, 0, 0);
            s[nt] = __builtin_amdgcn_mfma_f32_16x16x32_bf16(aq1, bk1, s[nt], 0, 0, 0);
        }

        // scale + causal mask + row max
        float mx[4] = {-3.0e38f, -3.0e38f, -3.0e38f, -3.0e38f};
        #pragma unroll
        for (int nt = 0; nt < 4; nt++) {
            int col = j0 + nt*16 + l15;
            #pragma unroll
            for (int r = 0; r < 4; r++) {
                int rowq = q0 + wave*16 + quad*4 + r;
                float sv = s[nt][r] * 0.125f;     // 1/sqrt(64)
                if (col > rowq) sv = -3.0e38f;
                s[nt][r] = sv;
                mx[r] = fmaxf(mx[r], sv);
            }
        }
        #pragma unroll
        for (int r = 0; r < 4; r++) {
            #pragma unroll
            for (int off = 1; off < 16; off <<= 1)
                mx[r] = fmaxf(mx[r], __shfl_xor(mx[r], off));
        }

        float alpha[4], rs[4];
        #pragma unroll
        for (int r = 0; r < 4; r++) {
            float mnew = fmaxf(m_s[r], mx[r]);
            alpha[r] = expf(m_s[r] - mnew);   // first iter: 0
            m_s[r] = mnew;
            rs[r] = 0.f;
        }
        #pragma unroll
        for (int nt = 0; nt < 4; nt++) {
            #pragma unroll
            for (int r = 0; r < 4; r++) {
                float p = expf(s[nt][r] - m_s[r]);   // masked -> 0
                rs[r] += p;
                Pl[wave][quad*4 + r][nt*16 + l15] = f2bf(p);
            }
        }
        #pragma unroll
        for (int r = 0; r < 4; r++) {
            #pragma unroll
            for (int off = 1; off < 16; off <<= 1)
                rs[r] += __shfl_xor(rs[r], off);
            l_s[r] = l_s[r] * alpha[r] + rs[r];
        }
        #pragma unroll
        for (int nt = 0; nt < 4; nt++)
            #pragma unroll
            for (int r = 0; r < 4; r++)
                o[nt][r] *= alpha[r];
        __syncthreads();   // P writes + Vt visible

        // O += P V : A-frag from Pl, B-frag = Vt[d][key] contiguous in key
        #pragma unroll
        for (int c = 0; c < 2; c++) {
            short8 ap = *(const short8*)&Pl[wave][l15][c*32 + quad*8];
            #pragma unroll
            for (int nt = 0; nt < 4; nt++) {
                short8 bv = *(const short8*)&Vt[nt*16 + l15][c*32 + quad*8];
                o[nt] = __builtin_amdgcn_mfma_f32_16x16x32_bf16(ap, bv, o[nt], 0, 0, 0);
            }
        }
    }

    #pragma unroll
    for (int nt = 0; nt < 4; nt++) {
        #pragma unroll
        for (int r = 0; r < 4; r++) {
            int rowq = q0 + wave*16 + quad*4 + r;
            int d    = nt*16 + l15;
            float v = o[nt][r] / l_s[r];
            CTX[(size_t)b * SEQ * DIM + (size_t)rowq * DIM + h*DH + d] = f2bf(v);
        }
    }
}

// ---------------------------------------------------------------------------
// Row LayerNorm over D=1024. xa fp32 or bf16; optional bf16 residual added.
// OUTF32: 1 -> float out (final), 0 -> bf16 out (intermediate).
// ---------------------------------------------------------------------------
template<int OUTF32>
__global__ __launch_bounds__(256) void ln_kernel(
    const void* __restrict__ xav, int xa_fp32, const short* __restrict__ xb,
    const float* __restrict__ g, const float* __restrict__ bvec,
    void* __restrict__ outv)
{
    __shared__ float red[8];
    const size_t base = (size_t)blockIdx.x * DIM;
    const int wave = threadIdx.x >> 6;

    float x[4];
    float sum = 0.f, sq = 0.f;
    #pragma unroll
    for (int i = 0; i < 4; i++) {
        int idx = threadIdx.x + i*256;
        float v = xa_fp32 ? ((const float*)xav)[base + idx]
                          : bf2f(((const short*)xav)[base + idx]);
        if (xb) v += bf2f(xb[base + idx]);
        x[i] = v; sum += v; sq += v*v;
    }
    sum = wave_sum(sum); sq = wave_sum(sq);
    if ((threadIdx.x & 63) == 0) { red[wave] = sum; red[4 + wave] = sq; }
    __syncthreads();
    float s1 = red[0] + red[1] + red[2] + red[3];
    float s2 = red[4] + red[5] + red[6] + red[7];
    float mean = s1 * (1.f / DIM);
    float var  = s2 * (1.f / DIM) - mean * mean;
    float rstd = rsqrtf(var + 1e-5f);
    #pragma unroll
    for (int i = 0; i < 4; i++) {
        int idx = threadIdx.x + i*256;
        float r = (x[i] - mean) * rstd * g[idx] + bvec[idx];
        if (OUTF32) ((float*)outv)[base + idx] = r;
        else        ((short*)outv)[base + idx] = f2bf(r);
    }
}

// ---------------------------------------------------------------------------
// Workspace plan (78 MB; 102 MB was demonstrably fine in R2):
//   Xb 8M | wqb 2M | wkb 2M | wvb 2M | w1b 8M | w2b 8M |
//   Q 8M | K 8M | V 8M | CTX 8M   (Hf 32M overlays Q..CTX after LN1)
//   X1 8M | Y2 8M
// d_out is float* (fp32 output, verified round 4).
// ---------------------------------------------------------------------------
extern "C" void kernel_launch(void* const* d_in, const int* in_sizes, int n_in,
                              void* d_out, int out_size, void* d_ws, size_t ws_size,
                              hipStream_t stream)
{
    const float* X   = (const float*)d_in[0];
    const float* wq  = (const float*)d_in[1];
    const float* wk  = (const float*)d_in[2];
    const float* wv  = (const float*)d_in[3];
    const float* g1  = (const float*)d_in[4];
    const float* b1  = (const float*)d_in[5];
    const float* w1  = (const float*)d_in[6];
    const float* bb1 = (const float*)d_in[7];
    const float* w2  = (const float*)d_in[8];
    const float* bb2 = (const float*)d_in[9];
    const float* g2  = (const float*)d_in[10];
    const float* b2  = (const float*)d_in[11];

    short* ws = (short*)d_ws;
    const size_t E1 = 1048576, E4 = 4194304;
    size_t o = 0;
    short* Xb  = ws + o; o += E4;
    short* wqb = ws + o; o += E1;
    short* wkb = ws + o; o += E1;
    short* wvb = ws + o; o += E1;
    short* w1b = ws + o; o += E4;
    short* w2b = ws + o; o += E4;
    short* Q   = ws + o; o += E4;
    short* Kb  = ws + o; o += E4;
    short* V   = ws + o; o += E4;
    short* CTX = ws + o; o += E4;
    short* X1  = ws + o; o += E4;
    short* Y2  = ws + o; o += E4;
    short* Hf  = Q;                       // 16M elems, overlays Q..CTX

    dim3 blk(256);
    convert_bf16<<<dim3(E4/2048), blk, 0, stream>>>(X,  Xb,  (int)E4);
    convert_bf16<<<dim3(E1/2048), blk, 0, stream>>>(wq, wqb, (int)E1);
    convert_bf16<<<dim3(E1/2048), blk, 0, stream>>>(wk, wkb, (int)E1);
    convert_bf16<<<dim3(E1/2048), blk, 0, stream>>>(wv, wvb, (int)E1);
    convert_bf16<<<dim3(E4/2048), blk, 0, stream>>>(w1, w1b, (int)E4);
    convert_bf16<<<dim3(E4/2048), blk, 0, stream>>>(w2, w2b, (int)E4);

    gemm_nt<<<dim3(MTOK/64, DIM/64), blk, 0, stream>>>(Xb, wqb, nullptr, nullptr, Q,  MTOK, DIM, DIM, 0);
    gemm_nt<<<dim3(MTOK/64, DIM/64), blk, 0, stream>>>(Xb, wkb, nullptr, nullptr, Kb, MTOK, DIM, DIM, 0);
    gemm_nt<<<dim3(MTOK/64, DIM/64), blk, 0, stream>>>(Xb, wvb, nullptr, nullptr, V,  MTOK, DIM, DIM, 0);
    attn_kernel<<<dim3(SEQ/64, BATCH*NH), blk, 0, stream>>>(Q, Kb, V, CTX);
    ln_kernel<0><<<dim3(MTOK), blk, 0, stream>>>(X, 1, CTX, g1, b1, X1);
    gemm_nt<<<dim3(MTOK/64, DFF/64), blk, 0, stream>>>(X1, w1b, bb1, nullptr, Hf, MTOK, DFF, DIM, 1);
    gemm_nt<<<dim3(MTOK/64, DIM/64), blk, 0, stream>>>(Hf, w2b, bb2, X1, Y2, MTOK, DIM, DFF, 2);
    ln_kernel<1><<<dim3(MTOK), blk, 0, stream>>>(Y2, 0, nullptr, g2, b2, d_out);
}

// Round 6
// 409.340 us; speedup vs baseline: 10.5842x; 2.5352x over previous
//
#include <hip/hip_runtime.h>
#include <hip/hip_bf16.h>

#define BATCH 4
#define SEQ   1024
#define DIM   1024
#define NH    16
#define DH    64
#define DFF   4096
#define MTOK  (BATCH*SEQ)   // 4096 token rows

typedef __attribute__((ext_vector_type(8))) short  short8;
typedef __attribute__((ext_vector_type(4))) float  floatx4;
typedef __attribute__((ext_vector_type(4))) float  float4v;

__device__ inline float bf2f(short s) {
    return __uint_as_float(((unsigned int)(unsigned short)s) << 16);
}
__device__ inline short f2bf(float f) {
    __hip_bfloat16 h = __float2bfloat16(f);
    return *reinterpret_cast<short*>(&h);
}

__device__ inline float wave_sum(float v) {
    #pragma unroll
    for (int off = 32; off >= 1; off >>= 1) v += __shfl_xor(v, off);
    return v;
}

// async global->LDS, 16B per lane. LDS dst is wave-uniform base + lane*16
// (m104/m108 caveat) -- our per-lane lds pointers are exactly that.
__device__ inline void async_ld16(short* lds, const short* g) {
    __builtin_amdgcn_global_load_lds(
        (const __attribute__((address_space(1))) void*)g,
        (__attribute__((address_space(3))) void*)lds, 16, 0, 0);
}

// ---------------------------------------------------------------------------
// Fused fp32->bf16 conversion of all 6 tensors in ONE launch.
// Chunk = 8 elements. Segment boundaries in chunks:
//   X:524288 | wq:131072 | wk:131072 | wv:131072 | w1:524288 | w2:524288
// ---------------------------------------------------------------------------
__global__ __launch_bounds__(256) void convert_all(
    const float* __restrict__ sX,  short* __restrict__ dX,
    const float* __restrict__ sq,  short* __restrict__ dq,
    const float* __restrict__ sk,  short* __restrict__ dk,
    const float* __restrict__ sv,  short* __restrict__ dv,
    const float* __restrict__ s1,  short* __restrict__ d1,
    const float* __restrict__ s2,  short* __restrict__ d2)
{
    int cid = blockIdx.x * 256 + threadIdx.x;     // 0 .. 1966079
    const float* src; short* dst; int base;
    if      (cid <  524288) { src = sX; dst = dX; base = 0; }
    else if (cid <  655360) { src = sq; dst = dq; base = 524288; }
    else if (cid <  786432) { src = sk; dst = dk; base = 655360; }
    else if (cid <  917504) { src = sv; dst = dv; base = 786432; }
    else if (cid < 1441792) { src = s1; dst = d1; base = 917504; }
    else                    { src = s2; dst = d2; base = 1441792; }
    size_t i = (size_t)(cid - base) * 8;
    float4v f0 = *(const float4v*)(src + i);
    float4v f1 = *(const float4v*)(src + i + 4);
    short8 o;
    o[0]=f2bf(f0[0]); o[1]=f2bf(f0[1]); o[2]=f2bf(f0[2]); o[3]=f2bf(f0[3]);
    o[4]=f2bf(f1[0]); o[5]=f2bf(f1[1]); o[6]=f2bf(f1[2]); o[7]=f2bf(f1[3]);
    *(short8*)(dst + i) = o;
}

// ---------------------------------------------------------------------------
// m97-style NT GEMM: C[M,N] = A[M,K]*B[N,K]^T, bf16 in, fp32 accum, bf16 out.
// 128 x BN tile, BK=32, 256 threads (4 waves, 2x2), global_load_lds staging,
// 2-barrier K-loop, per-wave 4 x (BN/32) accumulator of 16x16 tiles.
// LDS: As[128][32], Bs[BN][32], contiguous (no pad -- global_load_lds
// requires lane-order-contiguous dst).
// Fragment layouts (m89/m92 HW-verified): A m=l15,k=quad*8+j;
// B n=l15,k=quad*8+j; C/D col=l15,row=quad*4+r.
// EPI: 0 = QKV split store (C = base of 3 contiguous [MTOK][1024] buffers)
//      1 = +bias(f32), SELU
//      2 = +bias(f32), +resid(bf16)
// ---------------------------------------------------------------------------
template<int BN, int EPI>
__global__ __launch_bounds__(256) void gemm128(
    const short* __restrict__ A, const short* __restrict__ B,
    const float* __restrict__ bias, const short* __restrict__ resid,
    short* __restrict__ C, int N, int K)
{
    constexpr int NSUB = BN / 32;               // n-subtiles per wave
    __shared__ __align__(16) short As[128*32];  // 8 KB
    __shared__ __align__(16) short Bs[BN*32];   // 8 or 4 KB

    const int t    = threadIdx.x;
    const int lane = t & 63;
    const int wave = t >> 6;
    const int quad = lane >> 4;
    const int l15  = lane & 15;
    const int wm   = wave & 1;
    const int wn   = wave >> 1;
    const int tm   = blockIdx.x * 128;
    const int tn   = blockIdx.y * BN;

    // staging source offsets: chunk c -> row c>>2, k-offset (c&3)*8
    const size_t aoff0 = (size_t)(tm + (t >> 2)) * K + (t & 3) * 8;
    const size_t aoff1 = aoff0 + (size_t)64 * K;
    const size_t boff0 = (size_t)(tn + (t >> 2)) * K + (t & 3) * 8;
    const size_t boff1 = boff0 + (size_t)64 * K;

    floatx4 acc[4][NSUB];
    #pragma unroll
    for (int mt = 0; mt < 4; mt++)
        #pragma unroll
        for (int nt = 0; nt < NSUB; nt++) acc[mt][nt] = {0.f, 0.f, 0.f, 0.f};

    for (int k0 = 0; k0 < K; k0 += 32) {
        __syncthreads();                       // prev iter's LDS reads done
        async_ld16(As + t*8,        A + aoff0 + k0);
        async_ld16(As + 2048 + t*8, A + aoff1 + k0);
        async_ld16(Bs + t*8,        B + boff0 + k0);
        if (BN == 128) async_ld16(Bs + 2048 + t*8, B + boff1 + k0);
        __syncthreads();                       // drains vmcnt -> staging visible

        short8 a[4], b[NSUB];
        #pragma unroll
        for (int mt = 0; mt < 4; mt++)
            a[mt] = *(const short8*)&As[(wm*64 + mt*16 + l15)*32 + quad*8];
        #pragma unroll
        for (int nt = 0; nt < NSUB; nt++)
            b[nt] = *(const short8*)&Bs[(wn*(BN/2) + nt*16 + l15)*32 + quad*8];
        #pragma unroll
        for (int mt = 0; mt < 4; mt++)
            #pragma unroll
            for (int nt = 0; nt < NSUB; nt++)
                acc[mt][nt] = __builtin_amdgcn_mfma_f32_16x16x32_bf16(
                                  a[mt], b[nt], acc[mt][nt], 0, 0, 0);
    }

    const float SS = 1.0507009873554805f;
    const float SA = 1.6732632423543772f;

    #pragma unroll
    for (int mt = 0; mt < 4; mt++) {
        #pragma unroll
        for (int nt = 0; nt < NSUB; nt++) {
            int col = tn + wn*(BN/2) + nt*16 + l15;
            #pragma unroll
            for (int r = 0; r < 4; r++) {
                int row = tm + wm*64 + mt*16 + quad*4 + r;
                float v = acc[mt][nt][r];
                if (EPI == 0) {
                    int which = col >> 10;
                    C[(size_t)which * ((size_t)MTOK*1024)
                      + (size_t)row * 1024 + (col & 1023)] = f2bf(v);
                } else if (EPI == 1) {
                    v += bias[col];
                    v = (v > 0.f) ? SS * v : SS * SA * (expf(v) - 1.f);
                    C[(size_t)row * N + col] = f2bf(v);
                } else {
                    v += bias[col] + bf2f(resid[(size_t)row * N + col]);
                    C[(size_t)row * N + col] = f2bf(v);
                }
            }
        }
    }
}

// ---------------------------------------------------------------------------
// MFMA flash attention (validated R2==R3). Grid = (SEQ/64, BATCH*NH).
// ---------------------------------------------------------------------------
__global__ __launch_bounds__(256) void attn_kernel(
    const short* __restrict__ Q, const short* __restrict__ K,
    const short* __restrict__ V, short* __restrict__ CTX)
{
    __shared__ __align__(16) short Vt[64][72];      // [d][key], +pad
    __shared__ __align__(16) short Pl[4][16][72];   // [wave][qrow][key], +pad

    const int lane = threadIdx.x & 63;
    const int wave = threadIdx.x >> 6;
    const int quad = lane >> 4;
    const int l15  = lane & 15;
    const int q0 = blockIdx.x * 64;
    const int bh = blockIdx.y;
    const int b  = bh >> 4;
    const int h  = bh & 15;

    const size_t headoff = (size_t)b * SEQ * DIM + (size_t)h * DH;
    const short* Qb = Q + headoff;
    const short* Kb = K + headoff;
    const short* Vb = V + headoff;

    const short* qrow = Qb + (size_t)(q0 + wave*16 + l15) * DIM + quad*8;
    short8 aq0 = *(const short8*)(qrow);
    short8 aq1 = *(const short8*)(qrow + 32);

    float m_s[4], l_s[4];
    floatx4 o[4];
    #pragma unroll
    for (int r = 0; r < 4; r++) { m_s[r] = -3.0e38f; l_s[r] = 0.f; }
    #pragma unroll
    for (int nt = 0; nt < 4; nt++) o[nt] = {0.f, 0.f, 0.f, 0.f};

    for (int j0 = 0; j0 <= q0; j0 += 64) {
        __syncthreads();
        #pragma unroll
        for (int it = 0; it < 2; it++) {
            int idx = threadIdx.x + it * 256;
            int key = idx >> 3;
            int dc  = idx & 7;
            short8 v = *(const short8*)(Vb + (size_t)(j0 + key) * DIM + dc * 8);
            #pragma unroll
            for (int e = 0; e < 8; e++) Vt[dc*8 + e][key] = v[e];
        }
        __syncthreads();

        floatx4 s[4];
        #pragma unroll
        for (int nt = 0; nt < 4; nt++) s[nt] = {0.f, 0.f, 0.f, 0.f};
        #pragma unroll
        for (int nt = 0; nt < 4; nt++) {
            const short* kr = Kb + (size_t)(j0 + nt*16 + l15) * DIM + quad*8;
            short8 bk0 = *(const short8*)(kr);
            short8 bk1 = *(const short8*)(kr + 32);
            s[nt] = __builtin_amdgcn_mfma_f32_16x16x32_bf16(aq0, bk0, s[nt], 0, 0, 0);
            s[nt] = __builtin_amdgcn_mfma_f32_16x16x32_bf16(aq1, bk1, s[nt], 0, 0, 0);
        }

        float mx[4] = {-3.0e38f, -3.0e38f, -3.0e38f, -3.0e38f};
        #pragma unroll
        for (int nt = 0; nt < 4; nt++) {
            int col = j0 + nt*16 + l15;
            #pragma unroll
            for (int r = 0; r < 4; r++) {
                int rowq = q0 + wave*16 + quad*4 + r;
                float sv = s[nt][r] * 0.125f;
                if (col > rowq) sv = -3.0e38f;
                s[nt][r] = sv;
                mx[r] = fmaxf(mx[r], sv);
            }
        }
        #pragma unroll
        for (int r = 0; r < 4; r++) {
            #pragma unroll
            for (int off = 1; off < 16; off <<= 1)
                mx[r] = fmaxf(mx[r], __shfl_xor(mx[r], off));
        }

        float alpha[4], rs[4];
        #pragma unroll
        for (int r = 0; r < 4; r++) {
            float mnew = fmaxf(m_s[r], mx[r]);
            alpha[r] = expf(m_s[r] - mnew);
            m_s[r] = mnew;
            rs[r] = 0.f;
        }
        #pragma unroll
        for (int nt = 0; nt < 4; nt++) {
            #pragma unroll
            for (int r = 0; r < 4; r++) {
                float p = expf(s[nt][r] - m_s[r]);
                rs[r] += p;
                Pl[wave][quad*4 + r][nt*16 + l15] = f2bf(p);
            }
        }
        #pragma unroll
        for (int r = 0; r < 4; r++) {
            #pragma unroll
            for (int off = 1; off < 16; off <<= 1)
                rs[r] += __shfl_xor(rs[r], off);
            l_s[r] = l_s[r] * alpha[r] + rs[r];
        }
        #pragma unroll
        for (int nt = 0; nt < 4; nt++)
            #pragma unroll
            for (int r = 0; r < 4; r++)
                o[nt][r] *= alpha[r];
        __syncthreads();

        #pragma unroll
        for (int c = 0; c < 2; c++) {
            short8 ap = *(const short8*)&Pl[wave][l15][c*32 + quad*8];
            #pragma unroll
            for (int nt = 0; nt < 4; nt++) {
                short8 bv = *(const short8*)&Vt[nt*16 + l15][c*32 + quad*8];
                o[nt] = __builtin_amdgcn_mfma_f32_16x16x32_bf16(ap, bv, o[nt], 0, 0, 0);
            }
        }
    }

    #pragma unroll
    for (int nt = 0; nt < 4; nt++) {
        #pragma unroll
        for (int r = 0; r < 4; r++) {
            int rowq = q0 + wave*16 + quad*4 + r;
            int d    = nt*16 + l15;
            float v = o[nt][r] / l_s[r];
            CTX[(size_t)b * SEQ * DIM + (size_t)rowq * DIM + h*DH + d] = f2bf(v);
        }
    }
}

// ---------------------------------------------------------------------------
// Row LayerNorm over D=1024. xa fp32 or bf16; optional bf16 residual added.
// OUTF32: 1 -> float out (final), 0 -> bf16 out (intermediate).
// ---------------------------------------------------------------------------
template<int OUTF32>
__global__ __launch_bounds__(256) void ln_kernel(
    const void* __restrict__ xav, int xa_fp32, const short* __restrict__ xb,
    const float* __restrict__ g, const float* __restrict__ bvec,
    void* __restrict__ outv)
{
    __shared__ float red[8];
    const size_t base = (size_t)blockIdx.x * DIM;
    const int wave = threadIdx.x >> 6;

    float x[4];
    float sum = 0.f, sq = 0.f;
    #pragma unroll
    for (int i = 0; i < 4; i++) {
        int idx = threadIdx.x + i*256;
        float v = xa_fp32 ? ((const float*)xav)[base + idx]
                          : bf2f(((const short*)xav)[base + idx]);
        if (xb) v += bf2f(xb[base + idx]);
        x[i] = v; sum += v; sq += v*v;
    }
    sum = wave_sum(sum); sq = wave_sum(sq);
    if ((threadIdx.x & 63) == 0) { red[wave] = sum; red[4 + wave] = sq; }
    __syncthreads();
    float s1 = red[0] + red[1] + red[2] + red[3];
    float s2 = red[4] + red[5] + red[6] + red[7];
    float mean = s1 * (1.f / DIM);
    float var  = s2 * (1.f / DIM) - mean * mean;
    float rstd = rsqrtf(var + 1e-5f);
    #pragma unroll
    for (int i = 0; i < 4; i++) {
        int idx = threadIdx.x + i*256;
        float r = (x[i] - mean) * rstd * g[idx] + bvec[idx];
        if (OUTF32) ((float*)outv)[base + idx] = r;
        else        ((short*)outv)[base + idx] = f2bf(r);
    }
}

// ---------------------------------------------------------------------------
// Workspace (76 MB; 102 MB proven safe in R2):
//   Xb 4M | wqkvb 3M | w1b 4M | w2b 4M | Q 4M | K 4M | V 4M | CTX 4M |
//   X1 4M | Y2 4M   (elements; x2 bytes). Hf(16M) overlays Q..CTX.
//   Q,K,V contiguous -> single fused-QKV epilogue target.
// d_out is float* (verified round 4).
// ---------------------------------------------------------------------------
extern "C" void kernel_launch(void* const* d_in, const int* in_sizes, int n_in,
                              void* d_out, int out_size, void* d_ws, size_t ws_size,
                              hipStream_t stream)
{
    const float* X   = (const float*)d_in[0];
    const float* wq  = (const float*)d_in[1];
    const float* wk  = (const float*)d_in[2];
    const float* wv  = (const float*)d_in[3];
    const float* g1  = (const float*)d_in[4];
    const float* b1  = (const float*)d_in[5];
    const float* w1  = (const float*)d_in[6];
    const float* bb1 = (const float*)d_in[7];
    const float* w2  = (const float*)d_in[8];
    const float* bb2 = (const float*)d_in[9];
    const float* g2  = (const float*)d_in[10];
    const float* b2  = (const float*)d_in[11];

    short* ws = (short*)d_ws;
    const size_t E1 = 1048576, E4 = 4194304;
    size_t o = 0;
    short* Xb    = ws + o; o += E4;
    short* wqkvb = ws + o; o += 3*E1;
    short* w1b   = ws + o; o += E4;
    short* w2b   = ws + o; o += E4;
    short* Q     = ws + o; o += E4;
    short* Kb    = ws + o; o += E4;
    short* V     = ws + o; o += E4;
    short* CTX   = ws + o; o += E4;
    short* X1    = ws + o; o += E4;
    short* Y2    = ws + o; o += E4;
    short* Hf    = Q;                     // 16M elems, overlays Q..CTX

    dim3 blk(256);
    convert_all<<<dim3(7680), blk, 0, stream>>>(
        X, Xb, wq, wqkvb, wk, wqkvb + E1, wv, wqkvb + 2*E1,
        w1, w1b, w2, w2b);

    // fused QKV: N=3072, split epilogue into Q|K|V (contiguous)
    gemm128<128,0><<<dim3(MTOK/128, 3072/128), blk, 0, stream>>>(
        Xb, wqkvb, nullptr, nullptr, Q, 3072, DIM);
    attn_kernel<<<dim3(SEQ/64, BATCH*NH), blk, 0, stream>>>(Q, Kb, V, CTX);
    ln_kernel<0><<<dim3(MTOK), blk, 0, stream>>>(X, 1, CTX, g1, b1, X1);
    gemm128<128,1><<<dim3(MTOK/128, DFF/128), blk, 0, stream>>>(
        X1, w1b, bb1, nullptr, Hf, DFF, DIM);
    gemm128<64,2><<<dim3(MTOK/128, DIM/64), blk, 0, stream>>>(
        Hf, w2b, bb2, X1, Y2, DIM, DFF);
    ln_kernel<1><<<dim3(MTOK), blk, 0, stream>>>(Y2, 0, nullptr, g2, b2, d_out);
}

// Round 7
// 405.689 us; speedup vs baseline: 10.6794x; 1.0090x over previous
//
#include <hip/hip_runtime.h>
#include <hip/hip_bf16.h>

#define BATCH 4
#define SEQ   1024
#define DIM   1024
#define NH    16
#define DH    64
#define DFF   4096
#define MTOK  (BATCH*SEQ)   // 4096 token rows

// log2(e)/8 : folded into Q so attention softmax runs in base-2 (exact).
#define QSCALE 0.1803368801111204f

typedef __attribute__((ext_vector_type(8))) short  short8;
typedef __attribute__((ext_vector_type(4))) float  floatx4;
typedef __attribute__((ext_vector_type(4))) float  float4v;

__device__ inline float bf2f(short s) {
    return __uint_as_float(((unsigned int)(unsigned short)s) << 16);
}
__device__ inline short f2bf(float f) {
    __hip_bfloat16 h = __float2bfloat16(f);
    return *reinterpret_cast<short*>(&h);
}

__device__ inline float wave_sum(float v) {
    #pragma unroll
    for (int off = 32; off >= 1; off >>= 1) v += __shfl_xor(v, off);
    return v;
}

// async global->LDS, 16B per lane. LDS dst must be wave-uniform base +
// lane*16 (m104/m108) -- all call sites below satisfy this.
__device__ inline void async_ld16(short* lds, const short* g) {
    __builtin_amdgcn_global_load_lds(
        (const __attribute__((address_space(1))) void*)g,
        (__attribute__((address_space(3))) void*)lds, 16, 0, 0);
}

// ---------------------------------------------------------------------------
// Fused fp32->bf16 conversion of all 6 tensors in ONE launch.
// ---------------------------------------------------------------------------
__global__ __launch_bounds__(256) void convert_all(
    const float* __restrict__ sX,  short* __restrict__ dX,
    const float* __restrict__ sq,  short* __restrict__ dq,
    const float* __restrict__ sk,  short* __restrict__ dk,
    const float* __restrict__ sv,  short* __restrict__ dv,
    const float* __restrict__ s1,  short* __restrict__ d1,
    const float* __restrict__ s2,  short* __restrict__ d2)
{
    int cid = blockIdx.x * 256 + threadIdx.x;     // 0 .. 1966079
    const float* src; short* dst; int base;
    if      (cid <  524288) { src = sX; dst = dX; base = 0; }
    else if (cid <  655360) { src = sq; dst = dq; base = 524288; }
    else if (cid <  786432) { src = sk; dst = dk; base = 655360; }
    else if (cid <  917504) { src = sv; dst = dv; base = 786432; }
    else if (cid < 1441792) { src = s1; dst = d1; base = 917504; }
    else                    { src = s2; dst = d2; base = 1441792; }
    size_t i = (size_t)(cid - base) * 8;
    float4v f0 = *(const float4v*)(src + i);
    float4v f1 = *(const float4v*)(src + i + 4);
    short8 o;
    o[0]=f2bf(f0[0]); o[1]=f2bf(f0[1]); o[2]=f2bf(f0[2]); o[3]=f2bf(f0[3]);
    o[4]=f2bf(f1[0]); o[5]=f2bf(f1[1]); o[6]=f2bf(f1[2]); o[7]=f2bf(f1[3]);
    *(short8*)(dst + i) = o;
}

// ---------------------------------------------------------------------------
// m97-style NT GEMM, BK=64: C[M,N] = A[M,K]*B[N,K]^T, bf16, fp32 accum.
// 128 x BN tile, 256 thr (4 waves 2x2), global_load_lds staging (16B),
// 2-barrier K-loop with 32 MFMA per drain (2 k32 sub-steps).
// LDS: As[128][64] 16KB, Bs[BN][64] 16/8KB (contiguous -- async requirement).
// Frag layouts (m89/m92 HW-verified): A m=l15,k=quad*8+j; B n=l15,k same;
// C/D col=l15,row=quad*4+r.
// EPI: 0 = QKV split store (Q part pre-scaled by QSCALE)
//      1 = +bias(f32), SELU;  2 = +bias(f32), +resid(bf16)
// ---------------------------------------------------------------------------
template<int BN, int EPI>
__global__ __launch_bounds__(256) void gemm128(
    const short* __restrict__ A, const short* __restrict__ B,
    const float* __restrict__ bias, const short* __restrict__ resid,
    short* __restrict__ C, int N, int K)
{
    constexpr int NSUB = BN / 32;
    __shared__ __align__(16) short As[128*64];
    __shared__ __align__(16) short Bs[BN*64];

    const int t    = threadIdx.x;
    const int lane = t & 63;
    const int wave = t >> 6;
    const int quad = lane >> 4;
    const int l15  = lane & 15;
    const int wm   = wave & 1;
    const int wn   = wave >> 1;
    const int tm   = blockIdx.x * 128;
    const int tn   = blockIdx.y * BN;

    // staging: chunk c -> row c>>3, k-offset (c&7)*8 (64-k rows)
    const size_t aBase = (size_t)(tm + (t >> 3)) * K + (t & 7) * 8;
    const size_t bBase = (size_t)(tn + (t >> 3)) * K + (t & 7) * 8;

    floatx4 acc[4][NSUB];
    #pragma unroll
    for (int mt = 0; mt < 4; mt++)
        #pragma unroll
        for (int nt = 0; nt < NSUB; nt++) acc[mt][nt] = {0.f, 0.f, 0.f, 0.f};

    for (int k0 = 0; k0 < K; k0 += 64) {
        __syncthreads();                       // prev iter's LDS reads done
        #pragma unroll
        for (int i = 0; i < 4; i++)
            async_ld16(As + t*8 + i*2048, A + aBase + (size_t)(32*i)*K + k0);
        #pragma unroll
        for (int i = 0; i < BN/32; i++)
            async_ld16(Bs + t*8 + i*2048, B + bBase + (size_t)(32*i)*K + k0);
        __syncthreads();                       // vmcnt drain -> visible

        #pragma unroll
        for (int s = 0; s < 2; s++) {
            short8 a[4], b[NSUB];
            #pragma unroll
            for (int mt = 0; mt < 4; mt++)
                a[mt] = *(const short8*)&As[(wm*64 + mt*16 + l15)*64 + s*32 + quad*8];
            #pragma unroll
            for (int nt = 0; nt < NSUB; nt++)
                b[nt] = *(const short8*)&Bs[(wn*(BN/2) + nt*16 + l15)*64 + s*32 + quad*8];
            #pragma unroll
            for (int mt = 0; mt < 4; mt++)
                #pragma unroll
                for (int nt = 0; nt < NSUB; nt++)
                    acc[mt][nt] = __builtin_amdgcn_mfma_f32_16x16x32_bf16(
                                      a[mt], b[nt], acc[mt][nt], 0, 0, 0);
        }
    }

    const float SS = 1.0507009873554805f;
    const float SA = 1.6732632423543772f;

    #pragma unroll
    for (int mt = 0; mt < 4; mt++) {
        #pragma unroll
        for (int nt = 0; nt < NSUB; nt++) {
            int col = tn + wn*(BN/2) + nt*16 + l15;
            #pragma unroll
            for (int r = 0; r < 4; r++) {
                int row = tm + wm*64 + mt*16 + quad*4 + r;
                float v = acc[mt][nt][r];
                if (EPI == 0) {
                    int which = col >> 10;
                    if (which == 0) v *= QSCALE;   // base-2 softmax fold
                    C[(size_t)which * ((size_t)MTOK*1024)
                      + (size_t)row * 1024 + (col & 1023)] = f2bf(v);
                } else if (EPI == 1) {
                    v += bias[col];
                    v = (v > 0.f) ? SS * v
                                  : SS * SA * (exp2f(v * 1.44269504f) - 1.f);
                    C[(size_t)row * N + col] = f2bf(v);
                } else {
                    v += bias[col] + bf2f(resid[(size_t)row * N + col]);
                    C[(size_t)row * N + col] = f2bf(v);
                }
            }
        }
    }
}

// ---------------------------------------------------------------------------
// MFMA flash attention, base-2 softmax (Q pre-scaled by log2e/8).
// Grid = (SEQ/64, BATCH*NH); q-tiles reversed so long blocks launch first.
// Mask applied only on the diagonal tile (j0 == q0).
// ---------------------------------------------------------------------------
__global__ __launch_bounds__(256) void attn_kernel(
    const short* __restrict__ Q, const short* __restrict__ K,
    const short* __restrict__ V, short* __restrict__ CTX)
{
    __shared__ __align__(16) short Vt[64][72];      // [d][key], +pad
    __shared__ __align__(16) short Pl[4][16][72];   // [wave][qrow][key], +pad

    const int lane = threadIdx.x & 63;
    const int wave = threadIdx.x >> 6;
    const int quad = lane >> 4;
    const int l15  = lane & 15;
    const int q0 = (gridDim.x - 1 - blockIdx.x) * 64;   // long blocks first
    const int bh = blockIdx.y;
    const int b  = bh >> 4;
    const int h  = bh & 15;

    const size_t headoff = (size_t)b * SEQ * DIM + (size_t)h * DH;
    const short* Qb = Q + headoff;
    const short* Kb = K + headoff;
    const short* Vb = V + headoff;

    const short* qrow = Qb + (size_t)(q0 + wave*16 + l15) * DIM + quad*8;
    short8 aq0 = *(const short8*)(qrow);
    short8 aq1 = *(const short8*)(qrow + 32);

    float m_s[4], l_s[4];
    floatx4 o[4];
    #pragma unroll
    for (int r = 0; r < 4; r++) { m_s[r] = -1.0e38f; l_s[r] = 0.f; }
    #pragma unroll
    for (int nt = 0; nt < 4; nt++) o[nt] = {0.f, 0.f, 0.f, 0.f};

    for (int j0 = 0; j0 <= q0; j0 += 64) {
        __syncthreads();
        #pragma unroll
        for (int it = 0; it < 2; it++) {
            int idx = threadIdx.x + it * 256;
            int key = idx >> 3;
            int dc  = idx & 7;
            short8 v = *(const short8*)(Vb + (size_t)(j0 + key) * DIM + dc * 8);
            #pragma unroll
            for (int e = 0; e < 8; e++) Vt[dc*8 + e][key] = v[e];
        }
        __syncthreads();

        // S (base-2 logits) = Qs K^T for 16 rows x 64 keys
        floatx4 s[4];
        #pragma unroll
        for (int nt = 0; nt < 4; nt++) s[nt] = {0.f, 0.f, 0.f, 0.f};
        #pragma unroll
        for (int nt = 0; nt < 4; nt++) {
            const short* kr = Kb + (size_t)(j0 + nt*16 + l15) * DIM + quad*8;
            short8 bk0 = *(const short8*)(kr);
            short8 bk1 = *(const short8*)(kr + 32);
            s[nt] = __builtin_amdgcn_mfma_f32_16x16x32_bf16(aq0, bk0, s[nt], 0, 0, 0);
            s[nt] = __builtin_amdgcn_mfma_f32_16x16x32_bf16(aq1, bk1, s[nt], 0, 0, 0);
        }

        float mx[4] = {-1.0e38f, -1.0e38f, -1.0e38f, -1.0e38f};
        if (j0 == q0) {                      // diagonal tile: causal mask
            #pragma unroll
            for (int nt = 0; nt < 4; nt++) {
                int col = j0 + nt*16 + l15;
                #pragma unroll
                for (int r = 0; r < 4; r++) {
                    int rowq = q0 + wave*16 + quad*4 + r;
                    float sv = (col > rowq) ? -1.0e38f : s[nt][r];
                    s[nt][r] = sv;
                    mx[r] = fmaxf(mx[r], sv);
                }
            }
        } else {
            #pragma unroll
            for (int nt = 0; nt < 4; nt++)
                #pragma unroll
                for (int r = 0; r < 4; r++)
                    mx[r] = fmaxf(mx[r], s[nt][r]);
        }
        #pragma unroll
        for (int r = 0; r < 4; r++) {
            #pragma unroll
            for (int off = 1; off < 16; off <<= 1)
                mx[r] = fmaxf(mx[r], __shfl_xor(mx[r], off));
        }

        float alpha[4], rs[4];
        #pragma unroll
        for (int r = 0; r < 4; r++) {
            float mnew = fmaxf(m_s[r], mx[r]);
            alpha[r] = exp2f(m_s[r] - mnew);     // first iter: 0
            m_s[r] = mnew;
            rs[r] = 0.f;
        }
        #pragma unroll
        for (int nt = 0; nt < 4; nt++) {
            #pragma unroll
            for (int r = 0; r < 4; r++) {
                float p = exp2f(s[nt][r] - m_s[r]);   // masked -> 0
                rs[r] += p;
                Pl[wave][quad*4 + r][nt*16 + l15] = f2bf(p);
            }
        }
        #pragma unroll
        for (int r = 0; r < 4; r++) {
            #pragma unroll
            for (int off = 1; off < 16; off <<= 1)
                rs[r] += __shfl_xor(rs[r], off);
            l_s[r] = l_s[r] * alpha[r] + rs[r];
        }
        #pragma unroll
        for (int nt = 0; nt < 4; nt++)
            #pragma unroll
            for (int r = 0; r < 4; r++)
                o[nt][r] *= alpha[r];
        __syncthreads();

        #pragma unroll
        for (int c = 0; c < 2; c++) {
            short8 ap = *(const short8*)&Pl[wave][l15][c*32 + quad*8];
            #pragma unroll
            for (int nt = 0; nt < 4; nt++) {
                short8 bv = *(const short8*)&Vt[nt*16 + l15][c*32 + quad*8];
                o[nt] = __builtin_amdgcn_mfma_f32_16x16x32_bf16(ap, bv, o[nt], 0, 0, 0);
            }
        }
    }

    #pragma unroll
    for (int nt = 0; nt < 4; nt++) {
        #pragma unroll
        for (int r = 0; r < 4; r++) {
            int rowq = q0 + wave*16 + quad*4 + r;
            int d    = nt*16 + l15;
            float v = o[nt][r] / l_s[r];
            CTX[(size_t)b * SEQ * DIM + (size_t)rowq * DIM + h*DH + d] = f2bf(v);
        }
    }
}

// ---------------------------------------------------------------------------
// Row LayerNorm over D=1024. xa fp32 or bf16; optional bf16 residual added.
// OUTF32: 1 -> float out (final), 0 -> bf16 out (intermediate).
// ---------------------------------------------------------------------------
template<int OUTF32>
__global__ __launch_bounds__(256) void ln_kernel(
    const void* __restrict__ xav, int xa_fp32, const short* __restrict__ xb,
    const float* __restrict__ g, const float* __restrict__ bvec,
    void* __restrict__ outv)
{
    __shared__ float red[8];
    const size_t base = (size_t)blockIdx.x * DIM;
    const int wave = threadIdx.x >> 6;

    float x[4];
    float sum = 0.f, sq = 0.f;
    #pragma unroll
    for (int i = 0; i < 4; i++) {
        int idx = threadIdx.x + i*256;
        float v = xa_fp32 ? ((const float*)xav)[base + idx]
                          : bf2f(((const short*)xav)[base + idx]);
        if (xb) v += bf2f(xb[base + idx]);
        x[i] = v; sum += v; sq += v*v;
    }
    sum = wave_sum(sum); sq = wave_sum(sq);
    if ((threadIdx.x & 63) == 0) { red[wave] = sum; red[4 + wave] = sq; }
    __syncthreads();
    float s1 = red[0] + red[1] + red[2] + red[3];
    float s2 = red[4] + red[5] + red[6] + red[7];
    float mean = s1 * (1.f / DIM);
    float var  = s2 * (1.f / DIM) - mean * mean;
    float rstd = rsqrtf(var + 1e-5f);
    #pragma unroll
    for (int i = 0; i < 4; i++) {
        int idx = threadIdx.x + i*256;
        float r = (x[i] - mean) * rstd * g[idx] + bvec[idx];
        if (OUTF32) ((float*)outv)[base + idx] = r;
        else        ((short*)outv)[base + idx] = f2bf(r);
    }
}

// ---------------------------------------------------------------------------
// Workspace (76 MB; 102 MB proven safe in R2). Q,K,V contiguous (fused QKV).
// d_out is float* (verified round 4).
// ---------------------------------------------------------------------------
extern "C" void kernel_launch(void* const* d_in, const int* in_sizes, int n_in,
                              void* d_out, int out_size, void* d_ws, size_t ws_size,
                              hipStream_t stream)
{
    const float* X   = (const float*)d_in[0];
    const float* wq  = (const float*)d_in[1];
    const float* wk  = (const float*)d_in[2];
    const float* wv  = (const float*)d_in[3];
    const float* g1  = (const float*)d_in[4];
    const float* b1  = (const float*)d_in[5];
    const float* w1  = (const float*)d_in[6];
    const float* bb1 = (const float*)d_in[7];
    const float* w2  = (const float*)d_in[8];
    const float* bb2 = (const float*)d_in[9];
    const float* g2  = (const float*)d_in[10];
    const float* b2  = (const float*)d_in[11];

    short* ws = (short*)d_ws;
    const size_t E1 = 1048576, E4 = 4194304;
    size_t o = 0;
    short* Xb    = ws + o; o += E4;
    short* wqkvb = ws + o; o += 3*E1;
    short* w1b   = ws + o; o += E4;
    short* w2b   = ws + o; o += E4;
    short* Q     = ws + o; o += E4;
    short* Kb    = ws + o; o += E4;
    short* V     = ws + o; o += E4;
    short* CTX   = ws + o; o += E4;
    short* X1    = ws + o; o += E4;
    short* Y2    = ws + o; o += E4;
    short* Hf    = Q;                     // 16M elems, overlays Q..CTX

    dim3 blk(256);
    convert_all<<<dim3(7680), blk, 0, stream>>>(
        X, Xb, wq, wqkvb, wk, wqkvb + E1, wv, wqkvb + 2*E1,
        w1, w1b, w2, w2b);

    gemm128<128,0><<<dim3(MTOK/128, 3072/128), blk, 0, stream>>>(
        Xb, wqkvb, nullptr, nullptr, Q, 3072, DIM);
    attn_kernel<<<dim3(SEQ/64, BATCH*NH), blk, 0, stream>>>(Q, Kb, V, CTX);
    ln_kernel<0><<<dim3(MTOK), blk, 0, stream>>>(X, 1, CTX, g1, b1, X1);
    gemm128<128,1><<<dim3(MTOK/128, DFF/128), blk, 0, stream>>>(
        X1, w1b, bb1, nullptr, Hf, DFF, DIM);
    gemm128<64,2><<<dim3(MTOK/128, DIM/64), blk, 0, stream>>>(
        Hf, w2b, bb2, X1, Y2, DIM, DFF);
    ln_kernel<1><<<dim3(MTOK), blk, 0, stream>>>(Y2, 0, nullptr, g2, b2, d_out);
}